// Round 3
// baseline (412.975 us; speedup 1.0000x reference)
//
#include <hip/hip_runtime.h>

// AttGNN: GAT + GCN on sparse (~1%) 8192-node graph.
// R4: SAFE re-baseline after two container failures (suspect: cooperative
// grid.sync hang). 3-launch topology from the measured 409.8 us baseline,
// plus grid-sync-free improvements: wave-private ballot compaction (no LDS
// atomic), 2-deep outstanding loads on the 256 MB sup stream, 4 rows/block
// in the compaction half. Floor = one 256 MB sup read (~41 us) + ~320 us
// fixed harness poison-fill visible in dur_us.

#define N_NODES 8192
#define D_IN    128
#define D_GAT   64
#define SLOTS   256          // max nnz/row; binomial(8192,0.01) mean ~83, max ~120
#define K1_BLOCKS (N_NODES / 4)   // 2048 blocks of 4 rows
#define K2_BLOCKS (N_NODES / 4)   // 2048 blocks, 4 rows each (1/wave)

// Compact 4 consecutive elements (one float4) of row j held by this lane.
// Wave-private: `base` is wave-uniform (ballot-derived), no atomics.
#define COMPACT4(VX, QQ)                                                      \
    {                                                                         \
        float ee[4] = {VX.x, VX.y, VX.z, VX.w};                               \
        _Pragma("unroll")                                                     \
        for (int u = 0; u < 4; ++u) {                                         \
            const int i = (QQ) * 4 + u;                                       \
            const float vv = ee[u] + ((i == j) ? 1.0f : 0.0f); /* sup2 */     \
            const bool keep = vv > 0.f;                                       \
            const unsigned long long mask = __ballot(keep);                   \
            if (keep) {                                                       \
                const int pos = base +                                        \
                    __popcll(mask & ((1ull << lane) - 1ull));                 \
                if (pos < SLOTS) { colj[pos] = i; valj[pos] = vv; }           \
            }                                                                 \
            base += __popcll(mask);                                           \
        }                                                                     \
    }

// ---------------- K12: [blocks 0..2047] h=feat@W_map, s=h@U, t=h@V
//                  [blocks 2048..4095] compact sup rows -> (col,val) ---------
__global__ __launch_bounds__(256) void k12_map_compact(
    const float* __restrict__ feat, const float* __restrict__ W_map,
    const float* __restrict__ U, const float* __restrict__ V,
    const float* __restrict__ sup,
    float* __restrict__ h, float* __restrict__ s, float* __restrict__ t,
    int* __restrict__ cnt, int* __restrict__ col, float* __restrict__ val)
{
    const int wid  = threadIdx.x >> 6;
    const int lane = threadIdx.x & 63;
    if (blockIdx.x < K1_BLOCKS) {
        // ---- K1 part: 4 rows per block, wave r handles row blockIdx*4+r ----
        const int row = blockIdx.x * 4 + wid;
        __shared__ float f[4 * D_IN];
        if (threadIdx.x < 128)
            ((float4*)f)[threadIdx.x] =
                ((const float4*)(feat + (size_t)blockIdx.x * 4 * D_IN))[threadIdx.x];
        __syncthreads();
        const float* fr = f + wid * D_IN;
        float acc = 0.f;
#pragma unroll 8
        for (int k = 0; k < D_IN; ++k)
            acc += fr[k] * W_map[k * D_GAT + lane];
        h[row * D_GAT + lane] = acc;
        float sv = acc * U[lane];
        float tv = acc * V[lane];
#pragma unroll
        for (int off = 32; off > 0; off >>= 1) {
            sv += __shfl_xor(sv, off);
            tv += __shfl_xor(tv, off);
        }
        if (lane == 0) { s[row] = sv; t[row] = tv; }
    } else {
        // ---- K2 part: wave-private ballot compaction, one row per wave ----
        const int j = (blockIdx.x - K1_BLOCKS) * 4 + wid;
        int*   colj = col + j * SLOTS;
        float* valj = val + j * SLOTS;
        const float4* row4 = (const float4*)(sup + (size_t)j * N_NODES);
        int base = 0;                          // wave-uniform running count
        for (int q = lane; q < N_NODES / 4; q += 128) {  // 2 outstanding loads
            float4 v0 = row4[q];
            float4 v1 = row4[q + 64];
            COMPACT4(v0, q);
            COMPACT4(v1, q + 64);
        }
        if (lane == 0) cnt[j] = (base < SLOTS) ? base : SLOTS;
    }
}

// ---------------- K3: GAT row: softmax(tanh(s_i+t_j+b)) aggregate over h ----
// 4 rows/block (one wave each). Gather: lane=(pp,c16): pp=lane>>4 neighbor
// sub-slot, c16 float4 column; unroll-4 -> 4 outstanding loads.
__global__ __launch_bounds__(256) void k3_gat(
    const float* __restrict__ h, const float* __restrict__ s,
    const float* __restrict__ t, const float* __restrict__ b,
    const int* __restrict__ cnt, const int* __restrict__ col,
    float* __restrict__ gat)
{
    const int wid  = threadIdx.x >> 6;
    const int lane = threadIdx.x & 63;
    const int j = blockIdx.x * 4 + wid;
    const int m = cnt[j];
    const int* colj = col + j * SLOTS;
    __shared__ int   cl_s[4][SLOTS];
    __shared__ float w_s[4][SLOTS];
    int*   cl = cl_s[wid];
    float* w  = w_s[wid];
    const float tj = t[j] + b[0];

    float lmax = -1e30f;
    for (int p = lane; p < m; p += 64) {
        const int ci = colj[p];
        cl[p] = ci;
        const float e = tanhf(s[ci] + tj);
        w[p] = e;
        lmax = fmaxf(lmax, e);
    }
#pragma unroll
    for (int off = 32; off > 0; off >>= 1)
        lmax = fmaxf(lmax, __shfl_xor(lmax, off));

    float lsum = 0.f;
    for (int p = lane; p < m; p += 64) {   // same p-set as writer
        const float e = __expf(w[p] - lmax);
        w[p] = e;
        lsum += e;
    }
#pragma unroll
    for (int off = 32; off > 0; off >>= 1) lsum += __shfl_xor(lsum, off);
    __syncthreads();                       // w[], cl[] visible across lanes

    const int c16 = (lane & 15) * 4;
    const int pp  = lane >> 4;
    float4 a0 = make_float4(0,0,0,0), a1 = a0, a2 = a0, a3 = a0;
    for (int base = 0; base < m; base += 16) {
        const int p0 = base + pp, p1 = p0 + 4, p2 = p0 + 8, p3 = p0 + 12;
        if (p0 < m) { const float wp = w[p0];
            const float4 v = *(const float4*)(h + cl[p0] * D_GAT + c16);
            a0.x += wp*v.x; a0.y += wp*v.y; a0.z += wp*v.z; a0.w += wp*v.w; }
        if (p1 < m) { const float wp = w[p1];
            const float4 v = *(const float4*)(h + cl[p1] * D_GAT + c16);
            a1.x += wp*v.x; a1.y += wp*v.y; a1.z += wp*v.z; a1.w += wp*v.w; }
        if (p2 < m) { const float wp = w[p2];
            const float4 v = *(const float4*)(h + cl[p2] * D_GAT + c16);
            a2.x += wp*v.x; a2.y += wp*v.y; a2.z += wp*v.z; a2.w += wp*v.w; }
        if (p3 < m) { const float wp = w[p3];
            const float4 v = *(const float4*)(h + cl[p3] * D_GAT + c16);
            a3.x += wp*v.x; a3.y += wp*v.y; a3.z += wp*v.z; a3.w += wp*v.w; }
    }
    float4 acc;
    acc.x = (a0.x + a1.x) + (a2.x + a3.x);
    acc.y = (a0.y + a1.y) + (a2.y + a3.y);
    acc.z = (a0.z + a1.z) + (a2.z + a3.z);
    acc.w = (a0.w + a1.w) + (a2.w + a3.w);
#pragma unroll
    for (int off = 16; off <= 32; off <<= 1) {
        acc.x += __shfl_xor(acc.x, off); acc.y += __shfl_xor(acc.y, off);
        acc.z += __shfl_xor(acc.z, off); acc.w += __shfl_xor(acc.w, off);
    }
    if (pp == 0) {
        const float inv = 1.0f / lsum;
        float4 o;
        o.x = tanhf(acc.x * inv); o.y = tanhf(acc.y * inv);
        o.z = tanhf(acc.z * inv); o.w = tanhf(acc.w * inv);
        *(float4*)(gat + j * D_GAT + c16) = o;
    }
}

// ---------------- K4: agg = sup2@gat ; out = normalize(relu(agg@W_gcn)) ----
__global__ __launch_bounds__(256) void k4_gcn(
    const float* __restrict__ gat, const float* __restrict__ W_gcn,
    const int* __restrict__ cnt, const int* __restrict__ col,
    const float* __restrict__ val, float* __restrict__ out)
{
    const int wid  = threadIdx.x >> 6;
    const int lane = threadIdx.x & 63;
    const int j = blockIdx.x * 4 + wid;
    const int m = cnt[j];
    const int*   colj = col + j * SLOTS;
    const float* valj = val + j * SLOTS;
    __shared__ int   cl_s[4][SLOTS];
    __shared__ float wv_s[4][SLOTS];
    __shared__ float a_s[4][D_GAT];
    int*   cl = cl_s[wid];
    float* wv = wv_s[wid];
    float* a  = a_s[wid];
    for (int p = lane; p < m; p += 64) { cl[p] = colj[p]; wv[p] = valj[p]; }
    __syncthreads();

    const int c16 = (lane & 15) * 4;
    const int pp  = lane >> 4;
    float4 a0 = make_float4(0,0,0,0), a1 = a0, a2 = a0, a3 = a0;
    for (int base = 0; base < m; base += 16) {
        const int p0 = base + pp, p1 = p0 + 4, p2 = p0 + 8, p3 = p0 + 12;
        if (p0 < m) { const float wp = wv[p0];
            const float4 v = *(const float4*)(gat + cl[p0] * D_GAT + c16);
            a0.x += wp*v.x; a0.y += wp*v.y; a0.z += wp*v.z; a0.w += wp*v.w; }
        if (p1 < m) { const float wp = wv[p1];
            const float4 v = *(const float4*)(gat + cl[p1] * D_GAT + c16);
            a1.x += wp*v.x; a1.y += wp*v.y; a1.z += wp*v.z; a1.w += wp*v.w; }
        if (p2 < m) { const float wp = wv[p2];
            const float4 v = *(const float4*)(gat + cl[p2] * D_GAT + c16);
            a2.x += wp*v.x; a2.y += wp*v.y; a2.z += wp*v.z; a2.w += wp*v.w; }
        if (p3 < m) { const float wp = wv[p3];
            const float4 v = *(const float4*)(gat + cl[p3] * D_GAT + c16);
            a3.x += wp*v.x; a3.y += wp*v.y; a3.z += wp*v.z; a3.w += wp*v.w; }
    }
    float4 acc;
    acc.x = (a0.x + a1.x) + (a2.x + a3.x);
    acc.y = (a0.y + a1.y) + (a2.y + a3.y);
    acc.z = (a0.z + a1.z) + (a2.z + a3.z);
    acc.w = (a0.w + a1.w) + (a2.w + a3.w);
#pragma unroll
    for (int off = 16; off <= 32; off <<= 1) {
        acc.x += __shfl_xor(acc.x, off); acc.y += __shfl_xor(acc.y, off);
        acc.z += __shfl_xor(acc.z, off); acc.w += __shfl_xor(acc.w, off);
    }
    if (pp == 0) *(float4*)(a + c16) = acc;
    __syncthreads();     // a_s visibility (intra-wave, but keep it simple/safe)

    float o = 0.f;
#pragma unroll 8
    for (int d = 0; d < D_GAT; ++d)
        o += a[d] * W_gcn[d * D_GAT + lane];   // a broadcast, W_gcn L1-hot
    o = fmaxf(o, 0.f);

    float ss = o * o;
#pragma unroll
    for (int off = 32; off > 0; off >>= 1) ss += __shfl_xor(ss, off);
    const float nrm = sqrtf(ss);
    out[j * D_GAT + lane] = o / fmaxf(nrm, 1e-12f);
}

extern "C" void kernel_launch(void* const* d_in, const int* in_sizes, int n_in,
                              void* d_out, int out_size, void* d_ws, size_t ws_size,
                              hipStream_t stream) {
    const float* feat  = (const float*)d_in[0];  // [N,128]
    const float* sup   = (const float*)d_in[1];  // [N,N]
    const float* W_map = (const float*)d_in[2];  // [128,64]
    const float* b_map = (const float*)d_in[3];  // [1]
    const float* U     = (const float*)d_in[4];  // [64,1]
    const float* V     = (const float*)d_in[5];  // [64,1]
    const float* W_gcn = (const float*)d_in[6];  // [64,64]
    float* out = (float*)d_out;

    char* ws = (char*)d_ws;
    float* h   = (float*)(ws);                         // 2 MB
    float* gat = (float*)(ws + (2u << 20));            // 2 MB
    float* s   = (float*)(ws + (4u << 20));            // 32 KB
    float* t   = (float*)(ws + (4u << 20) + 32768);    // 32 KB
    int*   cnt = (int*)  (ws + (4u << 20) + 65536);    // 32 KB
    int*   col = (int*)  (ws + (4u << 20) + 98304);    // 8 MB
    float* val = (float*)(ws + (12u << 20) + 98304);   // 8 MB  (~20.1 MB total)

    k12_map_compact<<<K1_BLOCKS + K2_BLOCKS, 256, 0, stream>>>(
        feat, W_map, U, V, sup, h, s, t, cnt, col, val);
    k3_gat<<<N_NODES / 4, 256, 0, stream>>>(h, s, t, b_map, cnt, col, gat);
    k4_gcn<<<N_NODES / 4, 256, 0, stream>>>(gat, W_gcn, cnt, col, val, out);
}

// Round 4
// 406.228 us; speedup vs baseline: 1.0166x; 1.0166x over previous
//
#include <hip/hip_runtime.h>

// AttGNN: GAT + GCN on sparse (~1%) 8192-node graph.
// R5: K1 (tiny) separate; K2+K3 FUSED (compact row j into LDS -> immediate
// softmax+aggregate -> gat[j]; col/val written through for K4 only).
// Cooperative grid.sync is quarantined (two container kills in R2/R3).
// Floor = one 256 MB sup read (~41 us) + ~320 us harness poison-fill in dur_us.

#define N_NODES 8192
#define D_IN    128
#define D_GAT   64
#define SLOTS   256          // max nnz/row; binomial(8192,0.01) mean ~83, max ~120

// Compact 4 consecutive elements (one float4) of row j held by this lane
// into LDS (clr/vvr). Wave-private: `base` is wave-uniform, no atomics.
#define COMPACT4(VX, QQ)                                                      \
    {                                                                         \
        float ee[4] = {VX.x, VX.y, VX.z, VX.w};                               \
        _Pragma("unroll")                                                     \
        for (int u = 0; u < 4; ++u) {                                         \
            const int i = (QQ) * 4 + u;                                       \
            const float vv = ee[u] + ((i == j) ? 1.0f : 0.0f); /* sup2 */     \
            const bool keep = vv > 0.f;                                       \
            const unsigned long long mask = __ballot(keep);                   \
            if (keep) {                                                       \
                const int pos = base +                                        \
                    __popcll(mask & ((1ull << lane) - 1ull));                 \
                if (pos < SLOTS) { clr[pos] = i; vvr[pos] = vv; }             \
            }                                                                 \
            base += __popcll(mask);                                           \
        }                                                                     \
    }

// ---------------- K1: h = feat@W_map ; s = h@U ; t = h@V --------------------
__global__ __launch_bounds__(256) void k1_map(
    const float* __restrict__ feat, const float* __restrict__ W_map,
    const float* __restrict__ U, const float* __restrict__ V,
    float* __restrict__ h, float* __restrict__ s, float* __restrict__ t)
{
    const int wid  = threadIdx.x >> 6;
    const int lane = threadIdx.x & 63;
    const int row = blockIdx.x * 4 + wid;
    __shared__ float f[4 * D_IN];
    if (threadIdx.x < 128)
        ((float4*)f)[threadIdx.x] =
            ((const float4*)(feat + (size_t)blockIdx.x * 4 * D_IN))[threadIdx.x];
    __syncthreads();
    const float* fr = f + wid * D_IN;
    float acc = 0.f;
#pragma unroll 8
    for (int k = 0; k < D_IN; ++k)
        acc += fr[k] * W_map[k * D_GAT + lane];
    h[row * D_GAT + lane] = acc;
    float sv = acc * U[lane];
    float tv = acc * V[lane];
#pragma unroll
    for (int off = 32; off > 0; off >>= 1) {
        sv += __shfl_xor(sv, off);
        tv += __shfl_xor(tv, off);
    }
    if (lane == 0) { s[row] = sv; t[row] = tv; }
}

// ---------------- K23: compact sup2 row j -> LDS, then GAT row j ------------
// 4 rows/block (one wave each). After compaction the wave immediately runs
// softmax(tanh(s_i+t_j+b)) + weighted h-gather from LDS lists; gat[j] out.
// (col,val,cnt) are written through to HBM solely for K4.
__global__ __launch_bounds__(256) void k23_compact_gat(
    const float* __restrict__ sup, const float* __restrict__ h,
    const float* __restrict__ s, const float* __restrict__ t,
    const float* __restrict__ b,
    int* __restrict__ cnt, int* __restrict__ col, float* __restrict__ val,
    float* __restrict__ gat)
{
    const int wid  = threadIdx.x >> 6;
    const int lane = threadIdx.x & 63;
    const int j = blockIdx.x * 4 + wid;

    __shared__ int   cl_s[4][SLOTS];   // 4 KB  compacted neighbor cols
    __shared__ float vv_s[4][SLOTS];   // 4 KB  compacted sup2 values
    __shared__ float w_s[4][SLOTS];    // 4 KB  softmax weights
    int*   clr = cl_s[wid];
    float* vvr = vv_s[wid];
    float* w   = w_s[wid];

    // --- compaction: stream 32 KB row, ballot-compact into LDS ---
    const float4* row4 = (const float4*)(sup + (size_t)j * N_NODES);
    int base = 0;                          // wave-uniform running count
    for (int q = lane; q < N_NODES / 4; q += 128) {  // 2 outstanding loads
        float4 v0 = row4[q];
        float4 v1 = row4[q + 64];
        COMPACT4(v0, q);
        COMPACT4(v1, q + 64);
    }
    const int m = (base < SLOTS) ? base : SLOTS;
    __syncthreads();                       // LDS lists visible across lanes

    // --- write-through for K4 (coalesced) + softmax pass 1 ---
    int*   colj = col + j * SLOTS;
    float* valj = val + j * SLOTS;
    const float tj = t[j] + b[0];
    float lmax = -1e30f;
    for (int p = lane; p < m; p += 64) {
        const int ci = clr[p];
        colj[p] = ci;
        valj[p] = vvr[p];
        const float e = tanhf(s[ci] + tj);
        w[p] = e;
        lmax = fmaxf(lmax, e);
    }
    if (lane == 0) cnt[j] = m;
#pragma unroll
    for (int off = 32; off > 0; off >>= 1)
        lmax = fmaxf(lmax, __shfl_xor(lmax, off));

    float lsum = 0.f;
    for (int p = lane; p < m; p += 64) {   // same p-set as writer
        const float e = __expf(w[p] - lmax);
        w[p] = e;
        lsum += e;
    }
#pragma unroll
    for (int off = 32; off > 0; off >>= 1) lsum += __shfl_xor(lsum, off);
    __syncthreads();                       // w[] visible across lanes

    // --- gather-aggregate over h: lane=(pp,c16), unroll-4 outstanding ---
    const int c16 = (lane & 15) * 4;
    const int pp  = lane >> 4;
    float4 a0 = make_float4(0,0,0,0), a1 = a0, a2 = a0, a3 = a0;
    for (int bse = 0; bse < m; bse += 16) {
        const int p0 = bse + pp, p1 = p0 + 4, p2 = p0 + 8, p3 = p0 + 12;
        if (p0 < m) { const float wp = w[p0];
            const float4 v = *(const float4*)(h + clr[p0] * D_GAT + c16);
            a0.x += wp*v.x; a0.y += wp*v.y; a0.z += wp*v.z; a0.w += wp*v.w; }
        if (p1 < m) { const float wp = w[p1];
            const float4 v = *(const float4*)(h + clr[p1] * D_GAT + c16);
            a1.x += wp*v.x; a1.y += wp*v.y; a1.z += wp*v.z; a1.w += wp*v.w; }
        if (p2 < m) { const float wp = w[p2];
            const float4 v = *(const float4*)(h + clr[p2] * D_GAT + c16);
            a2.x += wp*v.x; a2.y += wp*v.y; a2.z += wp*v.z; a2.w += wp*v.w; }
        if (p3 < m) { const float wp = w[p3];
            const float4 v = *(const float4*)(h + clr[p3] * D_GAT + c16);
            a3.x += wp*v.x; a3.y += wp*v.y; a3.z += wp*v.z; a3.w += wp*v.w; }
    }
    float4 acc;
    acc.x = (a0.x + a1.x) + (a2.x + a3.x);
    acc.y = (a0.y + a1.y) + (a2.y + a3.y);
    acc.z = (a0.z + a1.z) + (a2.z + a3.z);
    acc.w = (a0.w + a1.w) + (a2.w + a3.w);
#pragma unroll
    for (int off = 16; off <= 32; off <<= 1) {
        acc.x += __shfl_xor(acc.x, off); acc.y += __shfl_xor(acc.y, off);
        acc.z += __shfl_xor(acc.z, off); acc.w += __shfl_xor(acc.w, off);
    }
    if (pp == 0) {
        const float inv = 1.0f / lsum;
        float4 o;
        o.x = tanhf(acc.x * inv); o.y = tanhf(acc.y * inv);
        o.z = tanhf(acc.z * inv); o.w = tanhf(acc.w * inv);
        *(float4*)(gat + j * D_GAT + c16) = o;
    }
}

// ---------------- K4: agg = sup2@gat ; out = normalize(relu(agg@W_gcn)) ----
__global__ __launch_bounds__(256) void k4_gcn(
    const float* __restrict__ gat, const float* __restrict__ W_gcn,
    const int* __restrict__ cnt, const int* __restrict__ col,
    const float* __restrict__ val, float* __restrict__ out)
{
    const int wid  = threadIdx.x >> 6;
    const int lane = threadIdx.x & 63;
    const int j = blockIdx.x * 4 + wid;
    const int m = cnt[j];
    const int*   colj = col + j * SLOTS;
    const float* valj = val + j * SLOTS;
    __shared__ int   cl_s[4][SLOTS];
    __shared__ float wv_s[4][SLOTS];
    __shared__ float a_s[4][D_GAT];
    int*   cl = cl_s[wid];
    float* wv = wv_s[wid];
    float* a  = a_s[wid];
    for (int p = lane; p < m; p += 64) { cl[p] = colj[p]; wv[p] = valj[p]; }
    __syncthreads();

    const int c16 = (lane & 15) * 4;
    const int pp  = lane >> 4;
    float4 a0 = make_float4(0,0,0,0), a1 = a0, a2 = a0, a3 = a0;
    for (int base = 0; base < m; base += 16) {
        const int p0 = base + pp, p1 = p0 + 4, p2 = p0 + 8, p3 = p0 + 12;
        if (p0 < m) { const float wp = wv[p0];
            const float4 v = *(const float4*)(gat + cl[p0] * D_GAT + c16);
            a0.x += wp*v.x; a0.y += wp*v.y; a0.z += wp*v.z; a0.w += wp*v.w; }
        if (p1 < m) { const float wp = wv[p1];
            const float4 v = *(const float4*)(gat + cl[p1] * D_GAT + c16);
            a1.x += wp*v.x; a1.y += wp*v.y; a1.z += wp*v.z; a1.w += wp*v.w; }
        if (p2 < m) { const float wp = wv[p2];
            const float4 v = *(const float4*)(gat + cl[p2] * D_GAT + c16);
            a2.x += wp*v.x; a2.y += wp*v.y; a2.z += wp*v.z; a2.w += wp*v.w; }
        if (p3 < m) { const float wp = wv[p3];
            const float4 v = *(const float4*)(gat + cl[p3] * D_GAT + c16);
            a3.x += wp*v.x; a3.y += wp*v.y; a3.z += wp*v.z; a3.w += wp*v.w; }
    }
    float4 acc;
    acc.x = (a0.x + a1.x) + (a2.x + a3.x);
    acc.y = (a0.y + a1.y) + (a2.y + a3.y);
    acc.z = (a0.z + a1.z) + (a2.z + a3.z);
    acc.w = (a0.w + a1.w) + (a2.w + a3.w);
#pragma unroll
    for (int off = 16; off <= 32; off <<= 1) {
        acc.x += __shfl_xor(acc.x, off); acc.y += __shfl_xor(acc.y, off);
        acc.z += __shfl_xor(acc.z, off); acc.w += __shfl_xor(acc.w, off);
    }
    if (pp == 0) *(float4*)(a + c16) = acc;
    __syncthreads();     // a_s visibility (intra-wave, but keep it simple/safe)

    float o = 0.f;
#pragma unroll 8
    for (int d = 0; d < D_GAT; ++d)
        o += a[d] * W_gcn[d * D_GAT + lane];   // a broadcast, W_gcn L1-hot
    o = fmaxf(o, 0.f);

    float ss = o * o;
#pragma unroll
    for (int off = 32; off > 0; off >>= 1) ss += __shfl_xor(ss, off);
    const float nrm = sqrtf(ss);
    out[j * D_GAT + lane] = o / fmaxf(nrm, 1e-12f);
}

extern "C" void kernel_launch(void* const* d_in, const int* in_sizes, int n_in,
                              void* d_out, int out_size, void* d_ws, size_t ws_size,
                              hipStream_t stream) {
    const float* feat  = (const float*)d_in[0];  // [N,128]
    const float* sup   = (const float*)d_in[1];  // [N,N]
    const float* W_map = (const float*)d_in[2];  // [128,64]
    const float* b_map = (const float*)d_in[3];  // [1]
    const float* U     = (const float*)d_in[4];  // [64,1]
    const float* V     = (const float*)d_in[5];  // [64,1]
    const float* W_gcn = (const float*)d_in[6];  // [64,64]
    float* out = (float*)d_out;

    char* ws = (char*)d_ws;
    float* h   = (float*)(ws);                         // 2 MB
    float* gat = (float*)(ws + (2u << 20));            // 2 MB
    float* s   = (float*)(ws + (4u << 20));            // 32 KB
    float* t   = (float*)(ws + (4u << 20) + 32768);    // 32 KB
    int*   cnt = (int*)  (ws + (4u << 20) + 65536);    // 32 KB
    int*   col = (int*)  (ws + (4u << 20) + 98304);    // 8 MB
    float* val = (float*)(ws + (12u << 20) + 98304);   // 8 MB  (~20.1 MB total)

    k1_map<<<N_NODES / 4, 256, 0, stream>>>(feat, W_map, U, V, h, s, t);
    k23_compact_gat<<<N_NODES / 4, 256, 0, stream>>>(
        sup, h, s, t, b_map, cnt, col, val, gat);
    k4_gcn<<<N_NODES / 4, 256, 0, stream>>>(gat, W_gcn, cnt, col, val, out);
}